// Round 7
// baseline (856.457 us; speedup 1.0000x reference)
//
#include <hip/hip_runtime.h>
#include <hip/hip_bf16.h>

#define HWF 128
#define NB  64
#define PW  30
#define PP  900

using bf16 = __hip_bfloat16;
typedef __attribute__((ext_vector_type(8))) short short8;
typedef __attribute__((ext_vector_type(4))) float f32x4;
typedef __attribute__((ext_vector_type(4))) unsigned int u32x4;
typedef __attribute__((ext_vector_type(2))) unsigned int u32x2;

__device__ __forceinline__ float b2f(bf16 v) { return __bfloat162float(v); }
__device__ __forceinline__ bf16  f2b(float v){ return __float2bfloat16(v); }
__device__ __forceinline__ float u2f(unsigned short u){ unsigned x = (unsigned)u << 16; float f; __builtin_memcpy(&f,&x,4); return f; }
__device__ __forceinline__ unsigned pack2(float a, float b) {
  union { bf16 h; unsigned short u; } ca, cb; ca.h = f2b(a); cb.h = f2b(b);
  return ((unsigned)cb.u << 16) | (unsigned)ca.u;
}

// ---------------------------------------------------------------------------
// Head fold: W_eff[k=ky*2+kx][o][ci] = sum_co head_w[o][co] * dw[co][ci][ky][kx]
// ---------------------------------------------------------------------------
__global__ void weff_kernel(const float* __restrict__ hm_dw, const float* __restrict__ hm_db,
                            const float* __restrict__ hm_w,  const float* __restrict__ hm_b,
                            const float* __restrict__ wh_dw, const float* __restrict__ wh_db,
                            const float* __restrict__ wh_w,  const float* __restrict__ wh_b,
                            float* __restrict__ Weff, float* __restrict__ beff) {
  const int blk = blockIdx.x;          // 0..11 == k*3 + o
  const int k = blk / 3, o = blk % 3;
  const int ci = threadIdx.x;
  const float* dw = (o == 0) ? hm_dw : wh_dw;
  const float* hw = (o == 0) ? hm_w  : (wh_w + (size_t)(o - 1) * 256);
  const float* dwp = dw + (size_t)ci * 4 + k;
  float s = 0.f;
  for (int co = 0; co < 256; ++co) s += hw[co] * dwp[(size_t)co * 1024];
  Weff[(size_t)blk * 256 + ci] = s;
  if (k == 0 && ci == 0) {
    const float* db = (o == 0) ? hm_db : wh_db;
    float bb = (o == 0) ? hm_b[0] : wh_b[o - 1];
    float t = 0.f;
    for (int co = 0; co < 256; ++co) t += hw[co] * db[co];
    beff[o] = bb + t;
  }
}

// ---------------------------------------------------------------------------
// Weight transform: w[co][ci][3][3] fp32 -> Wt[tap][cib][co][g][8ci] bf16
// ---------------------------------------------------------------------------
__global__ void wt_kernel(const float* __restrict__ w, bf16* __restrict__ Wt, int CIN) {
  const int co = blockIdx.x, ci = threadIdx.x;
  const int NCIB = CIN >> 5;
  const int cib = ci >> 5, g = (ci >> 3) & 3, e = ci & 7;
  for (int tap = 0; tap < 9; ++tap)
    Wt[((((size_t)tap * NCIB + cib) * 256 + co) * 4 + g) * 8 + e]
        = f2b(w[((size_t)co * CIN + ci) * 9 + tap]);
}

// ---------------------------------------------------------------------------
// Feature transpose: feat[b][64][128][128] fp32 -> featT[b][y][x][64] bf16
// ---------------------------------------------------------------------------
__global__ __launch_bounds__(256) void featT_kernel(const float* __restrict__ feat,
                                                    bf16* __restrict__ featT) {
  const int by = blockIdx.x;           // b*128 + y
  const int b = by >> 7, y = by & 127;
  const int t = threadIdx.x;
  __shared__ float tile[128][65];
  const int xr = t & 127, c2 = t >> 7;           // read: lane-major x
  for (int c0 = 0; c0 < 64; c0 += 2)
    tile[xr][c0 + c2] = feat[(((size_t)(b * 64 + c0 + c2) * 128 + y) * 128) + xr];
  __syncthreads();
  const int cw = t & 63, x4 = t >> 6;            // write: lane-major c
  for (int x0 = 0; x0 < 128; x0 += 4)
    featT[(((size_t)by * 128) + x0 + x4) * 64 + cw] = f2b(tile[x0 + x4][cw]);
}

// ---------------------------------------------------------------------------
// ROI align channel-last: featT -> roiP[roi][900][64] bf16 (borders zeroed)
// ---------------------------------------------------------------------------
__global__ __launch_bounds__(256) void roi_cl(const bf16* __restrict__ featT,
                                              const int* __restrict__ act_ind,
                                              const float* __restrict__ awh,
                                              bf16* __restrict__ roiP) {
  const int r = blockIdx.x, part = blockIdx.y;
  const int t = threadIdx.x;
  if (part == 7) {
    for (int i = t; i < 116 * 64; i += 256) {
      int j = i >> 6, c = i & 63;
      int py, px;
      if (j < 30)      { py = 0;      px = j;      }
      else if (j < 60) { py = 29;     px = j - 30; }
      else if (j < 88) { py = j - 59; px = 0;      }
      else             { py = j - 87; px = 29;     }
      roiP[((size_t)r * PP + py * PW + px) * 64 + c] = f2b(0.f);
    }
    return;
  }
  const int wave = t >> 6, c = t & 63;
  const int bi = r >> 5;
  const int ind = act_ind[r];
  const float cx = (float)(ind % HWF), cy = (float)(ind / HWF);
  const float hw = awh[r * 2 + 0] * 0.5f, hh = awh[r * 2 + 1] * 0.5f;
  const float x1b = cx - hw, y1b = cy - hh;
  const float bw = hw / 14.f, bh = hh / 14.f;
  const bf16* fb = featT + (size_t)bi * HWF * HWF * 64;
  for (int pp = part * 112 + wave; pp < part * 112 + 112; pp += 4) {
    int ry = pp / 28, rx = pp % 28;
    float acc = 0.f;
#pragma unroll
    for (int a = 0; a < 2; ++a) {
      int syi = 2 * ry + a;
      float ys = y1b + ((float)syi * 0.5f + 0.25f) * bh;
      ys = fminf(fmaxf(ys, 0.f), 127.f);
      int y0 = (int)floorf(ys); int y1i = min(y0 + 1, 127);
      float wy = ys - (float)y0;
#pragma unroll
      for (int b2 = 0; b2 < 2; ++b2) {
        int sxi = 2 * rx + b2;
        float xs = x1b + ((float)sxi * 0.5f + 0.25f) * bw;
        xs = fminf(fmaxf(xs, 0.f), 127.f);
        int x0 = (int)floorf(xs); int x1i = min(x0 + 1, 127);
        float wx = xs - (float)x0;
        float v00 = b2f(fb[((size_t)y0  * HWF + x0 ) * 64 + c]);
        float v01 = b2f(fb[((size_t)y0  * HWF + x1i) * 64 + c]);
        float v10 = b2f(fb[((size_t)y1i * HWF + x0 ) * 64 + c]);
        float v11 = b2f(fb[((size_t)y1i * HWF + x1i) * 64 + c]);
        float r0 = v00 * (1.f - wy) + v10 * wy;
        float r1 = v01 * (1.f - wy) + v11 * wy;
        acc += r0 * (1.f - wx) + r1 * wx;
      }
    }
    roiP[((size_t)r * PP + (ry + 1) * PW + (rx + 1)) * 64 + c] = f2b(acc * 0.25f);
  }
}

// ---------------------------------------------------------------------------
// MFMA implicit-GEMM conv3x3 + bias + ReLU, channel-last.
// X [64][900][CIN] bf16, Wt [9][NCIB][256][4][8] bf16, Y [64][900][256] bf16.
// grid (64 img, 7 strips of 4 output rows), block 512 (8 waves).
// Weight fragments register-prefetched one full ci-block ahead (18 loads in
// flight/wave); K-loop uses raw s_barrier + counted vmcnt (no vmcnt(0) drain).
// ---------------------------------------------------------------------------
template <int CIN>
__global__ __launch_bounds__(512, 2) void conv_mfma(const bf16* __restrict__ X,
                                                    const bf16* __restrict__ Wt,
                                                    const float* __restrict__ bias,
                                                    bf16* __restrict__ Y) {
  constexpr int NCIB = CIN / 32;
  const int img = blockIdx.x;
  const int strip = blockIdx.y;
  const int t = threadIdx.x;
  const int wave = t >> 6;
  const int lane = t & 63;
  const int g = lane >> 4;          // k-group (8 ci per group)
  const int lr = lane & 15;         // row/col within fragment
  const int wco = wave * 32;

  __shared__ char lds_raw[65536];   // [0,12K) stage0, [12K,24K) stage1; epilogue reuses all
  char* lds0 = lds_raw;
  char* lds1 = lds_raw + 12288;

  const bf16* Xb = X + (size_t)(img * PP + strip * 120) * CIN;

  int tp0[7];
#pragma unroll
  for (int n = 0; n < 7; ++n) {
    int p = n * 16 + lr;
    tp0[n] = p + 2 * (p / 28);      // r*30 + c
  }

  f32x4 acc[2][7];
#pragma unroll
  for (int m = 0; m < 2; ++m)
#pragma unroll
    for (int n = 0; n < 7; ++n) acc[m][n] = f32x4{0.f, 0.f, 0.f, 0.f};

  short8 awA[2][9], awB[2][9];      // weight fragments, double-buffered

#define LOADW(AW, cib)                                                           \
  {                                                                              \
    _Pragma("unroll")                                                            \
    for (int tap = 0; tap < 9; ++tap) {                                          \
      _Pragma("unroll")                                                          \
      for (int m = 0; m < 2; ++m) {                                              \
        AW[m][tap] = *(const short8*)(Wt +                                       \
            ((size_t)(tap * NCIB + (cib)) * 256 + wco + m * 16 + lr) * 32 + g * 8); \
      }                                                                          \
    }                                                                            \
  }

  // 12 x 1KB staging issues; waves 4-7's second issue duplicates issue 11 so
  // every wave issues exactly 2 (uniform vmcnt). aux=2 -> NT.
#define STAGE(BASE, CI0)                                                         \
  {                                                                              \
    _Pragma("unroll")                                                            \
    for (int ii = 0; ii < 2; ++ii) {                                             \
      int issue = wave + 8 * ii;                                                 \
      if (issue > 11) issue = 11;                                                \
      int tpix = (issue * 64 + lane) >> 2;                                       \
      int tpc = tpix > 179 ? 179 : tpix;                                         \
      int sslot = ((lane & 3) - (tpix >> 1)) & 3;                                \
      const bf16* src = Xb + (size_t)tpc * CIN + (CI0) + sslot * 8;              \
      char* dst = (BASE) + issue * 1024;                                         \
      __builtin_amdgcn_global_load_lds(                                          \
          (const __attribute__((address_space(1))) unsigned int*)src,            \
          (__attribute__((address_space(3))) unsigned int*)dst, 16, 0, 2);       \
    }                                                                            \
  }

#define COMPUTE(AW, LB)                                                          \
  {                                                                              \
    _Pragma("unroll")                                                            \
    for (int tap = 0; tap < 9; ++tap) {                                          \
      const int dt = (tap / 3) * 30 + (tap % 3);                                 \
      short8 bfr[7];                                                             \
      _Pragma("unroll")                                                          \
      for (int n = 0; n < 7; ++n) {                                              \
        int tp = tp0[n] + dt;                                                    \
        bfr[n] = *(const short8*)((LB) + tp * 64 + (((g + (tp >> 1)) & 3) << 4)); \
      }                                                                          \
      _Pragma("unroll")                                                          \
      for (int m = 0; m < 2; ++m)                                                \
        _Pragma("unroll")                                                        \
        for (int n = 0; n < 7; ++n)                                              \
          acc[m][n] = __builtin_amdgcn_mfma_f32_16x16x32_bf16(AW[m][tap], bfr[n], acc[m][n], 0, 0, 0); \
    }                                                                            \
  }

  LOADW(awA, 0);
  STAGE(lds0, 0);

#pragma unroll
  for (int c2 = 0; c2 < NCIB; c2 += 2) {
    // even step: compute cib=c2 from awA/lds0, prefetch c2+1 into awB/lds1
    if (c2 + 1 < NCIB) {
      LOADW(awB, c2 + 1);
      STAGE(lds1, (c2 + 1) * 32);
      asm volatile("s_waitcnt vmcnt(20)" ::: "memory");
    } else {
      asm volatile("s_waitcnt vmcnt(0)" ::: "memory");
    }
    __builtin_amdgcn_s_barrier();
    COMPUTE(awA, lds0);
    __builtin_amdgcn_s_barrier();
    __builtin_amdgcn_sched_barrier(0);
    // odd step: compute cib=c2+1 from awB/lds1, prefetch c2+2 into awA/lds0
    if (c2 + 1 < NCIB) {
      if (c2 + 2 < NCIB) {
        LOADW(awA, c2 + 2);
        STAGE(lds0, (c2 + 2) * 32);
        asm volatile("s_waitcnt vmcnt(20)" ::: "memory");
      } else {
        asm volatile("s_waitcnt vmcnt(0)" ::: "memory");
      }
      __builtin_amdgcn_s_barrier();
      COMPUTE(awB, lds1);
      __builtin_amdgcn_s_barrier();
      __builtin_amdgcn_sched_barrier(0);
    }
  }

  // ---------------- epilogue ----------------
  // LDS out-stage: logical [slot 0..119][co 0..255] bf16 (4 rows x 30 px, 512B/slot)
  // phys(slot, cb) = slot*512 + ((cb + slot*8) & 511)
  {
    int sbi = t >> 6, j = t & 63;
    int r = sbi >> 1, side = (sbi & 1) * 29;
    int slot = r * 30 + side;
    u32x2 z; z.x = 0u; z.y = 0u;
    *(u32x2*)(lds_raw + slot * 512 + ((j * 8 + slot * 8) & 511)) = z;
  }
  f32x4 bv[2];
#pragma unroll
  for (int m = 0; m < 2; ++m)
    bv[m] = *(const f32x4*)(bias + wco + m * 16 + g * 4);
#pragma unroll
  for (int n = 0; n < 7; ++n) {
    int p = n * 16 + lr;
    int Rr = p / 28, Cc = p % 28;
    int slot = Rr * 30 + Cc + 1;
#pragma unroll
    for (int m = 0; m < 2; ++m) {
      int cb = (wco + m * 16 + g * 4) * 2;
      f32x4 v = acc[m][n];
      float r0 = fmaxf(v[0] + bv[m][0], 0.f), r1 = fmaxf(v[1] + bv[m][1], 0.f);
      float r2 = fmaxf(v[2] + bv[m][2], 0.f), r3 = fmaxf(v[3] + bv[m][3], 0.f);
      u32x2 pk; pk.x = pack2(r0, r1); pk.y = pack2(r2, r3);
      *(u32x2*)(lds_raw + slot * 512 + ((cb + slot * 8) & 511)) = pk;
    }
  }
  __syncthreads();

  bf16* Yb = Y + (size_t)img * PP * 256;
  {
    int slot = t >> 2, q = t & 3;
    if (slot < 120) {
      char* gp = (char*)Yb + ((size_t)((strip * 4 + 1) * PW + slot)) * 512 + q * 128;
#pragma unroll
      for (int jp = 0; jp < 8; ++jp) {
        int cb0 = q * 128 + jp * 16;
        u32x2 v0 = *(u32x2*)(lds_raw + slot * 512 + ((cb0 + 0 + slot * 8) & 511));
        u32x2 v1 = *(u32x2*)(lds_raw + slot * 512 + ((cb0 + 8 + slot * 8) & 511));
        u32x4 o; o.x = v0.x; o.y = v0.y; o.z = v1.x; o.w = v1.y;
        __builtin_nontemporal_store(o, (u32x4*)(gp + jp * 16));
      }
    }
  }
  if (strip == 0 || strip == 6) {
    size_t rowbase = (strip == 0) ? 0 : (size_t)870;   // row 0 / row 29
    for (int i = t; i < 30 * 32; i += 512) {
      int px = i >> 5, c8 = (i & 31) << 3;
      u32x4 z; z.x = 0u; z.y = 0u; z.z = 0u; z.w = 0u;
      __builtin_nontemporal_store(z, (u32x4*)(Yb + (rowbase + px) * 256 + c8));
    }
  }
}

// ---------------------------------------------------------------------------
// Head: 12 dots of length 256 per pixel -> out (64,3,56,56) fp32
// ---------------------------------------------------------------------------
__global__ __launch_bounds__(256) void head_cl(const bf16* __restrict__ X,
                                               const float* __restrict__ Weff,
                                               const float* __restrict__ beff,
                                               float* __restrict__ out) {
  const int img = blockIdx.x, t = threadIdx.x;
  const float bo0 = beff[0], bo1 = beff[1], bo2 = beff[2];
  for (int p = t; p < 784; p += 256) {
    int iy = p / 28, ix = p % 28;
    const bf16* xp = X + ((size_t)img * PP + (iy + 1) * PW + ix + 1) * 256;
    float acc[12];
#pragma unroll
    for (int k = 0; k < 12; ++k) acc[k] = 0.f;
    for (int c8 = 0; c8 < 32; ++c8) {
      short8 v = *(const short8*)(xp + c8 * 8);
#pragma unroll
      for (int j = 0; j < 8; ++j) {
        float xv = u2f((unsigned short)v[j]);
#pragma unroll
        for (int k = 0; k < 12; ++k)
          acc[k] += xv * Weff[k * 256 + c8 * 8 + j];
      }
    }
#pragma unroll
    for (int k4 = 0; k4 < 4; ++k4) {
      int oy = 2 * iy + (k4 >> 1), ox = 2 * ix + (k4 & 1);
      out[(((size_t)(img * 3 + 0)) * 56 + oy) * 56 + ox] = acc[k4 * 3 + 0] + bo0;
      out[(((size_t)(img * 3 + 1)) * 56 + oy) * 56 + ox] = acc[k4 * 3 + 1] + bo1;
      out[(((size_t)(img * 3 + 2)) * 56 + oy) * 56 + ox] = acc[k4 * 3 + 2] + bo2;
    }
  }
}

// ---------------------------------------------------------------------------
extern "C" void kernel_launch(void* const* d_in, const int* in_sizes, int n_in,
                              void* d_out, int out_size, void* d_ws, size_t ws_size,
                              hipStream_t stream) {
  const float* feat    = (const float*)d_in[0];
  const int*   act_ind = (const int*)  d_in[1];
  const float* awh     = (const float*)d_in[2];
  const float* w1 = (const float*)d_in[3];  const float* b1 = (const float*)d_in[4];
  const float* w2 = (const float*)d_in[5];  const float* b2 = (const float*)d_in[6];
  const float* w3 = (const float*)d_in[7];  const float* b3 = (const float*)d_in[8];
  const float* w4 = (const float*)d_in[9];  const float* b4 = (const float*)d_in[10];
  const float* hm_dw = (const float*)d_in[11]; const float* hm_db = (const float*)d_in[12];
  const float* hm_w  = (const float*)d_in[13]; const float* hm_b  = (const float*)d_in[14];
  const float* wh_dw = (const float*)d_in[15]; const float* wh_db = (const float*)d_in[16];
  const float* wh_w  = (const float*)d_in[17]; const float* wh_b  = (const float*)d_in[18];

  char* ws = (char*)d_ws;
  size_t offset = 0;
  auto alloc = [&](size_t bytes) {
    size_t r = offset;
    offset += (bytes + 255) & ~(size_t)255;
    return r;
  };
  float* Weff = (float*)(ws + alloc(12 * 256 * sizeof(float)));
  float* beff = (float*)(ws + alloc(256));
  bf16*  Wt1  = (bf16*)(ws + alloc((size_t)9 * 256 * 64  * 2));
  bf16*  Wt2  = (bf16*)(ws + alloc((size_t)9 * 256 * 256 * 2));
  bf16*  Wt3  = (bf16*)(ws + alloc((size_t)9 * 256 * 256 * 2));
  bf16*  Wt4  = (bf16*)(ws + alloc((size_t)9 * 256 * 256 * 2));
  bf16*  bufA = (bf16*)(ws + alloc((size_t)NB * 256 * PP * 2));
  bf16*  bufB = (bf16*)(ws + alloc((size_t)NB * 256 * PP * 2));
  // aliases inside bufB (dead before conv2 writes bufB):
  bf16*  roiP  = bufB;                                   // 7.37 MB
  bf16*  featT = (bf16*)((char*)bufB + (8u << 20));      // 4.19 MB at +8MB

  weff_kernel<<<12, 256, 0, stream>>>(hm_dw, hm_db, hm_w, hm_b,
                                      wh_dw, wh_db, wh_w, wh_b, Weff, beff);
  wt_kernel<<<256, 64,  0, stream>>>(w1, Wt1, 64);
  wt_kernel<<<256, 256, 0, stream>>>(w2, Wt2, 256);
  wt_kernel<<<256, 256, 0, stream>>>(w3, Wt3, 256);
  wt_kernel<<<256, 256, 0, stream>>>(w4, Wt4, 256);
  featT_kernel<<<256, 256, 0, stream>>>(feat, featT);
  roi_cl<<<dim3(NB, 8), 256, 0, stream>>>(featT, act_ind, awh, roiP);
  conv_mfma<64> <<<dim3(NB, 7), 512, 0, stream>>>(roiP, Wt1, b1, bufA);
  conv_mfma<256><<<dim3(NB, 7), 512, 0, stream>>>(bufA, Wt2, b2, bufB);
  conv_mfma<256><<<dim3(NB, 7), 512, 0, stream>>>(bufB, Wt3, b3, bufA);
  conv_mfma<256><<<dim3(NB, 7), 512, 0, stream>>>(bufA, Wt4, b4, bufB);
  head_cl<<<NB, 256, 0, stream>>>(bufB, Weff, beff, (float*)d_out);
}

// Round 8
// 539.786 us; speedup vs baseline: 1.5867x; 1.5867x over previous
//
#include <hip/hip_runtime.h>
#include <hip/hip_bf16.h>

#define HWF 128
#define NB  64
#define PW  30
#define PP  900

using bf16 = __hip_bfloat16;
typedef __attribute__((ext_vector_type(8)))  short short8;
typedef __attribute__((ext_vector_type(4)))  float f32x4;
typedef __attribute__((ext_vector_type(16))) float f32x16;
typedef __attribute__((ext_vector_type(4)))  unsigned int u32x4;
typedef __attribute__((ext_vector_type(2)))  unsigned int u32x2;

__device__ __forceinline__ float b2f(bf16 v) { return __bfloat162float(v); }
__device__ __forceinline__ bf16  f2b(float v){ return __float2bfloat16(v); }
__device__ __forceinline__ float u2f(unsigned short u){ unsigned x = (unsigned)u << 16; float f; __builtin_memcpy(&f,&x,4); return f; }
__device__ __forceinline__ unsigned pack2(float a, float b) {
  union { bf16 h; unsigned short u; } ca, cb; ca.h = f2b(a); cb.h = f2b(b);
  return ((unsigned)cb.u << 16) | (unsigned)ca.u;
}

// ---------------------------------------------------------------------------
// Head fold (unchanged, verified)
// ---------------------------------------------------------------------------
__global__ void weff_kernel(const float* __restrict__ hm_dw, const float* __restrict__ hm_db,
                            const float* __restrict__ hm_w,  const float* __restrict__ hm_b,
                            const float* __restrict__ wh_dw, const float* __restrict__ wh_db,
                            const float* __restrict__ wh_w,  const float* __restrict__ wh_b,
                            float* __restrict__ Weff, float* __restrict__ beff) {
  const int blk = blockIdx.x;
  const int k = blk / 3, o = blk % 3;
  const int ci = threadIdx.x;
  const float* dw = (o == 0) ? hm_dw : wh_dw;
  const float* hw = (o == 0) ? hm_w  : (wh_w + (size_t)(o - 1) * 256);
  const float* dwp = dw + (size_t)ci * 4 + k;
  float s = 0.f;
  for (int co = 0; co < 256; ++co) s += hw[co] * dwp[(size_t)co * 1024];
  Weff[(size_t)blk * 256 + ci] = s;
  if (k == 0 && ci == 0) {
    const float* db = (o == 0) ? hm_db : wh_db;
    float bb = (o == 0) ? hm_b[0] : wh_b[o - 1];
    float t = 0.f;
    for (int co = 0; co < 256; ++co) t += hw[co] * db[co];
    beff[o] = bb + t;
  }
}

// ---------------------------------------------------------------------------
// Weight transform: w[co][ci][3][3] fp32 ->
//   Wt[tap][cib][kh][co][koct][8e] bf16   (kh = 16-ci half, koct = 8-ci oct)
// A-frag for 32x32x16: lane l -> co=l&31, k-oct=l>>5 -> 16B per lane, dense 1KB/32co
// ---------------------------------------------------------------------------
__global__ void wt_kernel(const float* __restrict__ w, bf16* __restrict__ Wt, int CIN) {
  const int co = blockIdx.x, ci = threadIdx.x;
  const int NCIB = CIN >> 5;
  const int cib = ci >> 5, cl = ci & 31;
  const int kh = cl >> 4, koct = (cl >> 3) & 1, e = ci & 7;
  for (int tap = 0; tap < 9; ++tap)
    Wt[(((((size_t)tap * NCIB + cib) * 2 + kh) * 256 + co) * 2 + koct) * 8 + e]
        = f2b(w[((size_t)co * CIN + ci) * 9 + tap]);
}

// ---------------------------------------------------------------------------
// Feature transpose (unchanged, verified)
// ---------------------------------------------------------------------------
__global__ __launch_bounds__(256) void featT_kernel(const float* __restrict__ feat,
                                                    bf16* __restrict__ featT) {
  const int by = blockIdx.x;
  const int b = by >> 7, y = by & 127;
  const int t = threadIdx.x;
  __shared__ float tile[128][65];
  const int xr = t & 127, c2 = t >> 7;
  for (int c0 = 0; c0 < 64; c0 += 2)
    tile[xr][c0 + c2] = feat[(((size_t)(b * 64 + c0 + c2) * 128 + y) * 128) + xr];
  __syncthreads();
  const int cw = t & 63, x4 = t >> 6;
  for (int x0 = 0; x0 < 128; x0 += 4)
    featT[(((size_t)by * 128) + x0 + x4) * 64 + cw] = f2b(tile[x0 + x4][cw]);
}

// ---------------------------------------------------------------------------
// ROI align -> roiP cob-blocked: [roi][cb 0..1][900][32ci] bf16, borders zeroed
// ---------------------------------------------------------------------------
__global__ __launch_bounds__(256) void roi_cl(const bf16* __restrict__ featT,
                                              const int* __restrict__ act_ind,
                                              const float* __restrict__ awh,
                                              bf16* __restrict__ roiP) {
  const int r = blockIdx.x, part = blockIdx.y;
  const int t = threadIdx.x;
  if (part == 7) {
    for (int i = t; i < 116 * 64; i += 256) {
      int j = i >> 6, c = i & 63;
      int py, px;
      if (j < 30)      { py = 0;      px = j;      }
      else if (j < 60) { py = 29;     px = j - 30; }
      else if (j < 88) { py = j - 59; px = 0;      }
      else             { py = j - 87; px = 29;     }
      roiP[(((size_t)(r * 2 + (c >> 5)) * PP) + py * PW + px) * 32 + (c & 31)] = f2b(0.f);
    }
    return;
  }
  const int wave = t >> 6, c = t & 63;
  const int bi = r >> 5;
  const int ind = act_ind[r];
  const float cx = (float)(ind % HWF), cy = (float)(ind / HWF);
  const float hw = awh[r * 2 + 0] * 0.5f, hh = awh[r * 2 + 1] * 0.5f;
  const float x1b = cx - hw, y1b = cy - hh;
  const float bw = hw / 14.f, bh = hh / 14.f;
  const bf16* fb = featT + (size_t)bi * HWF * HWF * 64;
  for (int pp = part * 112 + wave; pp < part * 112 + 112; pp += 4) {
    int ry = pp / 28, rx = pp % 28;
    float acc = 0.f;
#pragma unroll
    for (int a = 0; a < 2; ++a) {
      int syi = 2 * ry + a;
      float ys = y1b + ((float)syi * 0.5f + 0.25f) * bh;
      ys = fminf(fmaxf(ys, 0.f), 127.f);
      int y0 = (int)floorf(ys); int y1i = min(y0 + 1, 127);
      float wy = ys - (float)y0;
#pragma unroll
      for (int b2 = 0; b2 < 2; ++b2) {
        int sxi = 2 * rx + b2;
        float xs = x1b + ((float)sxi * 0.5f + 0.25f) * bw;
        xs = fminf(fmaxf(xs, 0.f), 127.f);
        int x0 = (int)floorf(xs); int x1i = min(x0 + 1, 127);
        float wx = xs - (float)x0;
        float v00 = b2f(fb[((size_t)y0  * HWF + x0 ) * 64 + c]);
        float v01 = b2f(fb[((size_t)y0  * HWF + x1i) * 64 + c]);
        float v10 = b2f(fb[((size_t)y1i * HWF + x0 ) * 64 + c]);
        float v11 = b2f(fb[((size_t)y1i * HWF + x1i) * 64 + c]);
        float r0 = v00 * (1.f - wy) + v10 * wy;
        float r1 = v01 * (1.f - wy) + v11 * wy;
        acc += r0 * (1.f - wx) + r1 * wx;
      }
    }
    int slot = (ry + 1) * PW + (rx + 1);
    roiP[(((size_t)(r * 2 + (c >> 5)) * PP) + slot) * 32 + (c & 31)] = f2b(acc * 0.25f);
  }
}

// ---------------------------------------------------------------------------
// 32x32x16-MFMA implicit-GEMM conv3x3 + bias + ReLU, cob-blocked channel-last.
// X [img][NCIB][900][32] bf16, Wt [9][NCIB][2][256][2][8] bf16,
// Y [img][8][900][32] bf16.
// grid 256 (img,strip XCD-grouped), block 512 (8 waves = 4 Mgrp x 2 Ngrp).
// Wave tile: 64 co (2 m-frags) x 128 slots (4 n-frags); acc 128 VGPR.
// Staged region: 272 slots x 32 ci, XOR-u swizzled via pre-swizzled source.
// ---------------------------------------------------------------------------
template <int CIN>
__global__ __launch_bounds__(512, 2) void conv_mfma(const bf16* __restrict__ X,
                                                    const bf16* __restrict__ Wt,
                                                    const float* __restrict__ bias,
                                                    bf16* __restrict__ Y) {
  constexpr int NCIB = CIN / 32;
  const int d = blockIdx.x;
  const int xcd = d & 7, jj = d >> 3;
  const int img = xcd * 8 + (jj >> 2);
  const int strip = jj & 3;
  const int t = threadIdx.x;
  const int wave = t >> 6, lane = t & 63;
  const int hi = lane >> 5, l31 = lane & 31;
  const int mg = wave >> 1, ng = wave & 1;
  const int R0 = strip * 7;

  __shared__ char lds[2][17408];

  // staging lane offsets (3 rounds; round 2 only wave 0) — 1088 16B chunks
  int stoff[3];
#pragma unroll
  for (int r = 0; r < 3; ++r) {
    int chunk = r * 512 + t;
    if (chunk > 1087) chunk = 1087;
    int ss = chunk >> 2, up = chunk & 3;
    int u = up ^ ((ss >> 2) & 3);
    int q = ss - 1; q = q < 0 ? 0 : (q > 269 ? 269 : q);
    stoff[r] = q * 64 + u * 16;
  }

#define STAGE(BUF, CIB)                                                          \
  {                                                                              \
    const char* Xc = (const char*)X +                                            \
        ((size_t)(img * NCIB + (CIB)) * 900 + R0 * 30) * 64;                     \
    _Pragma("unroll")                                                            \
    for (int r = 0; r < 3; ++r) {                                                \
      if (r < 2 || wave == 0) {                                                  \
        __builtin_amdgcn_global_load_lds(                                        \
            (const __attribute__((address_space(1))) unsigned int*)(Xc + stoff[r]), \
            (__attribute__((address_space(3))) unsigned int*)                    \
                (&lds[(BUF)][0] + (r * 8 + wave) * 1024), 16, 0, 0);             \
      }                                                                          \
    }                                                                            \
  }

  f32x16 acc[2][4];
#pragma unroll
  for (int mf = 0; mf < 2; ++mf)
#pragma unroll
    for (int nf = 0; nf < 4; ++nf)
#pragma unroll
      for (int e = 0; e < 16; ++e) acc[mf][nf][e] = 0.f;

  // B-read base (slot clamp) per n-frag
  int soc[4];
#pragma unroll
  for (int nf = 0; nf < 4; ++nf) {
    int so = ng * 128 + nf * 32 + l31;
    soc[nf] = so > 209 ? 209 : so;
  }
  const int awoff = l31 * 32 + hi * 16;    // A byte offset within (tap,cib,kh,cogrp)

  constexpr int DTP[9] = { -1, 0, 1, 29, 30, 31, 59, 60, 61 };

#define LOADA(A, CIB, J)                                                         \
  {                                                                              \
    _Pragma("unroll")                                                            \
    for (int mf = 0; mf < 2; ++mf) {                                             \
      int off = ((((J >> 1) * NCIB + (CIB)) * 2 + ((J) & 1)) * 256               \
                 + mg * 64 + mf * 32) * 32 + awoff;                              \
      A[mf] = *(const short8*)((const char*)Wt + off);                           \
    }                                                                            \
  }

#define LOADB(B, LB, J)                                                          \
  {                                                                              \
    _Pragma("unroll")                                                            \
    for (int nf = 0; nf < 4; ++nf) {                                             \
      int ss = soc[nf] + DTP[(J) >> 1] + 1;                                      \
      int u = ((((J) & 1) << 1) + hi) ^ ((ss >> 2) & 3);                         \
      B[nf] = *(const short8*)((LB) + ss * 64 + (u << 4));                       \
    }                                                                            \
  }

#define DOMFMA(A, B)                                                             \
  {                                                                              \
    _Pragma("unroll")                                                            \
    for (int mf = 0; mf < 2; ++mf)                                               \
      _Pragma("unroll")                                                          \
      for (int nf = 0; nf < 4; ++nf)                                             \
        acc[mf][nf] = __builtin_amdgcn_mfma_f32_32x32x16_bf16(                   \
            A[mf], B[nf], acc[mf][nf], 0, 0, 0);                                 \
  }

  STAGE(0, 0);
  __syncthreads();

  for (int cib = 0; cib < NCIB; ++cib) {
    const int buf = cib & 1;
    if (cib + 1 < NCIB) STAGE(buf ^ 1, cib + 1);
    const char* lb = &lds[buf][0];

    short8 a0[2], b0[4], a1[2], b1[4];
    LOADA(a0, cib, 0); LOADB(b0, lb, 0);
#pragma unroll
    for (int j = 0; j < 18; j += 2) {
      if (j + 1 < 18) { LOADA(a1, cib, j + 1); LOADB(b1, lb, j + 1); }
      DOMFMA(a0, b0);
      if (j + 2 < 18) { LOADA(a0, cib, j + 2); LOADB(b0, lb, j + 2); }
      if (j + 1 < 18) DOMFMA(a1, b1);
    }
    __syncthreads();
  }

  // ---------------- epilogue: direct dense stores (no LDS transpose) --------
  const int outrow0 = (strip * 7 + 1) * 30;
#pragma unroll
  for (int mf = 0; mf < 2; ++mf) {
    const int cob = mg * 2 + mf;
    f32x4 bv[4];
#pragma unroll
    for (int rq = 0; rq < 4; ++rq)
      bv[rq] = *(const f32x4*)(bias + mg * 64 + mf * 32 + 8 * rq + 4 * hi);
#pragma unroll
    for (int nf = 0; nf < 4; ++nf) {
      int so = ng * 128 + nf * 32 + l31;
      if (so < 210) {
        int c = so % 30;
        bool border = (c == 0) || (c == 29);
        char* gp = (char*)Y + ((size_t)(img * 8 + cob) * 900 + outrow0 + so) * 64
                 + hi * 8;
#pragma unroll
        for (int rq = 0; rq < 4; ++rq) {
          u32x2 pk;
          if (border) { pk.x = 0u; pk.y = 0u; }
          else {
            float r0 = fmaxf(acc[mf][nf][4*rq+0] + bv[rq][0], 0.f);
            float r1 = fmaxf(acc[mf][nf][4*rq+1] + bv[rq][1], 0.f);
            float r2 = fmaxf(acc[mf][nf][4*rq+2] + bv[rq][2], 0.f);
            float r3 = fmaxf(acc[mf][nf][4*rq+3] + bv[rq][3], 0.f);
            pk.x = pack2(r0, r1); pk.y = pack2(r2, r3);
          }
          *(u32x2*)(gp + rq * 16) = pk;
        }
      }
    }
  }
  // row 0 / row 29 zeroing (strips 0 and 3)
  if (strip == 0 || strip == 3) {
    const int rowslot = (strip == 0) ? 0 : 870;
    for (int i = t; i < 8 * 30 * 8; i += 512) {
      int cob = i / 240, rem = i % 240;
      int sl = rem >> 3, oct = rem & 7;
      u32x2 z; z.x = 0u; z.y = 0u;
      *(u32x2*)((char*)Y + ((size_t)(img * 8 + cob) * 900 + rowslot + sl) * 64
                + oct * 8) = z;
    }
  }
}

// ---------------------------------------------------------------------------
// Head: 12 dots of length 256 per pixel -> out (64,3,56,56) fp32
// X cob-blocked [img][8][900][32]
// ---------------------------------------------------------------------------
__global__ __launch_bounds__(256) void head_cl(const bf16* __restrict__ X,
                                               const float* __restrict__ Weff,
                                               const float* __restrict__ beff,
                                               float* __restrict__ out) {
  const int img = blockIdx.x, t = threadIdx.x;
  const float bo0 = beff[0], bo1 = beff[1], bo2 = beff[2];
  for (int p = t; p < 784; p += 256) {
    int iy = p / 28, ix = p % 28;
    int slot = (iy + 1) * PW + ix + 1;
    float acc[12];
#pragma unroll
    for (int k = 0; k < 12; ++k) acc[k] = 0.f;
    for (int cob = 0; cob < 8; ++cob) {
      const bf16* xp = X + ((size_t)(img * 8 + cob) * PP + slot) * 32;
#pragma unroll
      for (int oct = 0; oct < 4; ++oct) {
        short8 v = *(const short8*)(xp + oct * 8);
#pragma unroll
        for (int j = 0; j < 8; ++j) {
          float xv = u2f((unsigned short)v[j]);
          int ci = cob * 32 + oct * 8 + j;
#pragma unroll
          for (int k = 0; k < 12; ++k)
            acc[k] += xv * Weff[k * 256 + ci];
        }
      }
    }
#pragma unroll
    for (int k4 = 0; k4 < 4; ++k4) {
      int oy = 2 * iy + (k4 >> 1), ox = 2 * ix + (k4 & 1);
      out[(((size_t)(img * 3 + 0)) * 56 + oy) * 56 + ox] = acc[k4 * 3 + 0] + bo0;
      out[(((size_t)(img * 3 + 1)) * 56 + oy) * 56 + ox] = acc[k4 * 3 + 1] + bo1;
      out[(((size_t)(img * 3 + 2)) * 56 + oy) * 56 + ox] = acc[k4 * 3 + 2] + bo2;
    }
  }
}

// ---------------------------------------------------------------------------
extern "C" void kernel_launch(void* const* d_in, const int* in_sizes, int n_in,
                              void* d_out, int out_size, void* d_ws, size_t ws_size,
                              hipStream_t stream) {
  const float* feat    = (const float*)d_in[0];
  const int*   act_ind = (const int*)  d_in[1];
  const float* awh     = (const float*)d_in[2];
  const float* w1 = (const float*)d_in[3];  const float* b1 = (const float*)d_in[4];
  const float* w2 = (const float*)d_in[5];  const float* b2 = (const float*)d_in[6];
  const float* w3 = (const float*)d_in[7];  const float* b3 = (const float*)d_in[8];
  const float* w4 = (const float*)d_in[9];  const float* b4 = (const float*)d_in[10];
  const float* hm_dw = (const float*)d_in[11]; const float* hm_db = (const float*)d_in[12];
  const float* hm_w  = (const float*)d_in[13]; const float* hm_b  = (const float*)d_in[14];
  const float* wh_dw = (const float*)d_in[15]; const float* wh_db = (const float*)d_in[16];
  const float* wh_w  = (const float*)d_in[17]; const float* wh_b  = (const float*)d_in[18];

  char* ws = (char*)d_ws;
  size_t offset = 0;
  auto alloc = [&](size_t bytes) {
    size_t r = offset;
    offset += (bytes + 255) & ~(size_t)255;
    return r;
  };
  float* Weff = (float*)(ws + alloc(12 * 256 * sizeof(float)));
  float* beff = (float*)(ws + alloc(256));
  bf16*  Wt1  = (bf16*)(ws + alloc((size_t)9 * 256 * 64  * 2));
  bf16*  Wt2  = (bf16*)(ws + alloc((size_t)9 * 256 * 256 * 2));
  bf16*  Wt3  = (bf16*)(ws + alloc((size_t)9 * 256 * 256 * 2));
  bf16*  Wt4  = (bf16*)(ws + alloc((size_t)9 * 256 * 256 * 2));
  bf16*  bufA = (bf16*)(ws + alloc((size_t)NB * 256 * PP * 2));
  bf16*  bufB = (bf16*)(ws + alloc((size_t)NB * 256 * PP * 2));
  // aliases inside bufB (dead before conv2 writes bufB):
  bf16*  roiP  = bufB;                                   // 7.37 MB
  bf16*  featT = (bf16*)((char*)bufB + (8u << 20));      // 4.19 MB at +8MB

  weff_kernel<<<12, 256, 0, stream>>>(hm_dw, hm_db, hm_w, hm_b,
                                      wh_dw, wh_db, wh_w, wh_b, Weff, beff);
  wt_kernel<<<256, 64,  0, stream>>>(w1, Wt1, 64);
  wt_kernel<<<256, 256, 0, stream>>>(w2, Wt2, 256);
  wt_kernel<<<256, 256, 0, stream>>>(w3, Wt3, 256);
  wt_kernel<<<256, 256, 0, stream>>>(w4, Wt4, 256);
  featT_kernel<<<256, 256, 0, stream>>>(feat, featT);
  roi_cl<<<dim3(NB, 8), 256, 0, stream>>>(featT, act_ind, awh, roiP);
  conv_mfma<64> <<<256, 512, 0, stream>>>(roiP, Wt1, b1, bufA);
  conv_mfma<256><<<256, 512, 0, stream>>>(bufA, Wt2, b2, bufB);
  conv_mfma<256><<<256, 512, 0, stream>>>(bufB, Wt3, b3, bufA);
  conv_mfma<256><<<256, 512, 0, stream>>>(bufA, Wt4, b4, bufB);
  head_cl<<<NB, 256, 0, stream>>>(bufB, Weff, beff, (float*)d_out);
}